// Round 10
// baseline (7815.566 us; speedup 1.0000x reference)
//
#include <hip/hip_runtime.h>
#include <hip/hip_bf16.h>

// Cos_RootHist_GLM — FLOAT32 outputs (reference computes in jnp.float32;
// harness doc: "else float*"). Pipeline math verified by rounds 7-9 probes:
// b sane, hist<=0, scan impls agree. Prior failures = bf16 writes into f32 buf.

#define DEVINL __device__ __forceinline__

static constexpr int T_DATA = 20000;
static constexpr int N_E = 2000;
static constexpr int N_I = 500;
static constexpr int SUB = 15;
static constexpr int T_NO = 200;
static constexpr int NB = 19;

// ws layout (f32 offsets) — total 30592 f32 = 122,368 B
static constexpr int EKT_OFF = 0;      // [200][16]
static constexpr int IKT_OFF = 3200;   // [200][16]
static constexpr int HT_OFF  = 6400;   // 256
static constexpr int PRM_OFF = 6656;   // 0..14 wsub2, 16..30 theta, 33 scale, 34 vo
static constexpr int WE_OFF  = 6720;   // 2000
static constexpr int WI_OFF  = 8720;   // 500
static constexpr int IDXE_B  = 36880;  // byte off, 2000 uchar
static constexpr int IDXI_B  = 38880;  // byte off, 500 uchar
static constexpr int BT_OFF  = 9856;   // 20000 + pad
static constexpr int WS_END  = 30592;

DEVINL float softplus_f(float x) {
  float z = x * 1.44269504088896f;
  float l = 0.6931471805599453f * log2f(1.0f + exp2f(z));
  return (x > 16.0f) ? x : l;
}

// ---------------- prep ----------------
__global__ __launch_bounds__(256) void prep_kernel(
    const float* __restrict__ Cse, const float* __restrict__ Csi,
    const float* __restrict__ cosb, const float* __restrict__ Wsyn,
    const float* __restrict__ Wsub, const float* __restrict__ Vo,
    const float* __restrict__ Theta, const float* __restrict__ Whist,
    float* __restrict__ ws, float* __restrict__ outF) {
  const int tid = threadIdx.x;
  float* ekT = ws + EKT_OFF;
  float* ikT = ws + IKT_OFF;
  float* ht  = ws + HT_OFF;
  float* prm = ws + PRM_OFF;
  float* we  = ws + WE_OFF;
  float* wi  = ws + WI_OFF;
  unsigned char* idxe = (unsigned char*)ws + IDXE_B;
  unsigned char* idxi = (unsigned char*)ws + IDXI_B;
  float* bT  = ws + BT_OFF;

  for (int p = tid; p < SUB * T_NO; p += 256) {
    int s = p / T_NO, j = p - s * T_NO;
    float ae = 0.f, ai = 0.f;
    for (int b = 0; b < NB; ++b) {
      float cb = cosb[b * T_NO + j];
      ae = fmaf(Wsyn[(s * NB + b) * 2 + 0], cb, ae);
      ai = fmaf(Wsyn[(s * NB + b) * 2 + 1], cb, ai);
    }
    ekT[j * 16 + s] = ae;
    ikT[j * 16 + s] = ai;
    outF[p] = ae;
    outF[SUB * T_NO + p] = ai;
  }
  for (int j = tid; j < T_NO; j += 256) { ekT[j * 16 + 15] = 0.f; ikT[j * 16 + 15] = 0.f; }
  if (tid < 256) {
    float hv = 0.f;
    if (tid < T_NO) {
      for (int b = 0; b < NB; ++b) hv = fmaf(Whist[b], cosb[b * T_NO + tid], hv);
      outF[30 * T_NO + tid] = hv;
    }
    ht[tid] = (tid < T_NO) ? hv : 0.f;
  }
  for (int n = tid; n < N_E; n += 256) {
    int id = 0; float w = 0.f;
    for (int s = 0; s < SUB; ++s) { float c = Cse[s * N_E + n]; if (c != 0.f) { id = s; w = c; } }
    idxe[n] = (unsigned char)id; we[n] = w;
  }
  for (int n = tid; n < N_I; n += 256) {
    int id = 0; float w = 0.f;
    for (int s = 0; s < SUB; ++s) { float c = Csi[s * N_I + n]; if (c != 0.f) { id = s; w = c; } }
    idxi[n] = (unsigned char)id; wi[n] = w;
  }
  if (tid < SUB) {
    float w = Wsub[tid];
    prm[tid] = w * w;
    prm[16 + tid] = Theta[tid];
  }
  if (tid == 0) {
    float w0 = Wsub[0];
    prm[33] = w0 * w0;
    prm[34] = Vo[0];
  }
  for (int p = T_DATA + tid; p < T_DATA + 736; p += 256) bT[p] = 0.f;
}

// ---------------- fused pool + conv + tree (block per 64 t's) ----------------
__global__ __launch_bounds__(256) void fused_kernel(
    const float* __restrict__ Se, const float* __restrict__ Si,
    float* __restrict__ ws, float* __restrict__ outNs) {
  __shared__ float cntE[264][16], cntI[264][16], synR[64][16];
  const int tid = threadIdx.x;
  const int t0 = blockIdx.x * 64;
  const unsigned char* idxe = (const unsigned char*)ws + IDXE_B;
  const unsigned char* idxi = (const unsigned char*)ws + IDXI_B;
  const float* we = ws + WE_OFF;
  const float* wi = ws + WI_OFF;

  for (int p = tid; p < 264 * 16; p += 256) {
    ((float*)cntE)[p] = 0.f;
    ((float*)cntI)[p] = 0.f;
  }
  __syncthreads();
  for (int r = 0; r < 263; ++r) {
    int g = t0 - 199 + r;
    if (g < 0 || g >= T_DATA) continue;
    const float* rowE = Se + (size_t)g * N_E;
    for (int n = tid; n < N_E; n += 256) {
      float v = rowE[n];
      if (v != 0.f) atomicAdd(&cntE[r][idxe[n]], v * we[n]);
    }
    const float* rowI = Si + (size_t)g * N_I;
    for (int n = tid; n < N_I; n += 256) {
      float v = rowI[n];
      if (v != 0.f) atomicAdd(&cntI[r][idxi[n]], v * wi[n]);
    }
  }
  __syncthreads();
  {
    const int q = tid >> 6, i = tid & 63;
    const float4* ekT = (const float4*)(ws + EKT_OFF);
    const float4* ikT = (const float4*)(ws + IKT_OFF);
    float4 acc = make_float4(0.f, 0.f, 0.f, 0.f);
    for (int d = 0; d < T_NO; ++d) {
      int r = i + 199 - d;
      float4 e = ekT[d * 4 + q], ce = ((const float4*)&cntE[r][0])[q];
      float4 ii = ikT[d * 4 + q], ci = ((const float4*)&cntI[r][0])[q];
      acc.x = fmaf(e.x, ce.x, fmaf(ii.x, ci.x, acc.x));
      acc.y = fmaf(e.y, ce.y, fmaf(ii.y, ci.y, acc.y));
      acc.z = fmaf(e.z, ce.z, fmaf(ii.z, ci.z, acc.z));
      acc.w = fmaf(e.w, ce.w, fmaf(ii.w, ci.w, acc.w));
    }
    ((float4*)&synR[i][0])[q] = acc;
  }
  __syncthreads();
  if (tid < 64) {
    int t = t0 + tid;
    if (t < T_DATA) {
      const float* prm = ws + PRM_OFF;
      float sv[16];
#pragma unroll
      for (int s = 0; s < 16; ++s) sv[s] = synR[tid][s];
      float ns[SUB];
#pragma unroll
      for (int j = SUB - 1; j >= 1; --j) {
        float x = sv[j] + prm[16 + j];
        if (2 * j + 1 < SUB) x = fmaf(prm[2 * j + 1], ns[2 * j + 1], x);
        if (2 * j + 2 < SUB) x = fmaf(prm[2 * j + 2], ns[2 * j + 2], x);
        ns[j] = softplus_f(x);
      }
      float b = sv[0] + prm[16];
      b = fmaf(prm[1], ns[1], b);
      b = fmaf(prm[2], ns[2], b);
      ws[BT_OFF + t] = b;
      outNs[(size_t)t * SUB] = 0.f;
#pragma unroll
      for (int s = 1; s < SUB; ++s) outNs[(size_t)t * SUB + s] = ns[s];
    }
  }
}

// ---------------- serial scan: 64-lane LDS ring (proven ≡ serial in r9) ----------------
__global__ __launch_bounds__(64) void scan_kernel(const float* __restrict__ ws,
                                                  float* __restrict__ outV) {
  __shared__ float yh[256];
  const int lane = threadIdx.x;
  const float* ht = ws + HT_OFF;
  const float* prm = ws + PRM_OFF;
  const float* bT = ws + BT_OFF;
  const float c0 = ht[lane];
  const float c1 = ht[lane + 64];
  const float c2 = ht[lane + 128];
  const float c3 = ht[lane + 192];   // lanes >= 8 of this group read ht[>=200] = 0
  yh[lane] = 0.f; yh[lane + 64] = 0.f; yh[lane + 128] = 0.f; yh[lane + 192] = 0.f;
  __syncthreads();
  const float scale = prm[33], vo = prm[34];
  for (int t = 0; t < T_DATA; ++t) {
    int base = t - 1 - lane;
    float s = c0 * yh[(base      ) & 255];
    s = fmaf(c1, yh[(base - 64 ) & 255], s);
    s = fmaf(c2, yh[(base - 128) & 255], s);
    s = fmaf(c3, yh[(base - 192) & 255], s);
    s += __shfl_xor(s, 1);
    s += __shfl_xor(s, 2);
    s += __shfl_xor(s, 4);
    s += __shfl_xor(s, 8);
    s += __shfl_xor(s, 16);
    s += __shfl_xor(s, 32);
    float x = bT[t] + s;
    x = fminf(fmaxf(x, -87.0f), 87.0f);
    float z = x * 1.44269504088896f;
    float lg = 0.6931471805599453f * log2f(1.0f + exp2f(z));
    float y = (x > 16.0f) ? x : lg;
    if (lane == 0) {
      outV[t] = fmaf(y, scale, vo);
      yh[t & 255] = y;
    }
    __syncthreads();
  }
}

// ---------------- sentinel ----------------
__global__ __launch_bounds__(256) void sentinel_kernel(float* __restrict__ outV, int code) {
  const int tid = threadIdx.x;
  for (int t = tid; t < T_DATA; t += 256) outV[t] = (float)code;
}

extern "C" void kernel_launch(void* const* d_in, const int* in_sizes, int n_in,
                              void* d_out, int out_size, void* d_ws, size_t ws_size,
                              hipStream_t stream) {
  const float* Se    = (const float*)d_in[0];
  const float* Si    = (const float*)d_in[1];
  const float* Cse   = (const float*)d_in[3];
  const float* Csi   = (const float*)d_in[4];
  const float* cosb  = (const float*)d_in[5];
  const float* Wsyn  = (const float*)d_in[6];
  const float* Wsub  = (const float*)d_in[7];
  const float* Vo    = (const float*)d_in[8];
  const float* Theta = (const float*)d_in[9];
  const float* Whist = (const float*)d_in[10];
  float* ws = (float*)d_ws;
  float* out = (float*)d_out;
  float* outV  = out;                          // final_V: 20000 f32
  float* outNs = out + T_DATA;                 // ns_out: 300000 f32
  float* outF  = out + T_DATA + T_DATA * SUB;  // out_filters: 6200 f32

  int force = 0;
  if (ws_size < (size_t)(WS_END * 4 + 2048)) force = 3000;
  else if (out_size != 326200) force = 3500;
  if (force) {
    sentinel_kernel<<<1, 256, 0, stream>>>(outV, force);
    return;
  }

  prep_kernel<<<1, 256, 0, stream>>>(Cse, Csi, cosb, Wsyn, Wsub, Vo, Theta, Whist, ws, outF);
  fused_kernel<<<313, 256, 0, stream>>>(Se, Si, ws, outNs);
  scan_kernel<<<1, 64, 0, stream>>>(ws, outV);
}

// Round 11
// 2397.171 us; speedup vs baseline: 3.2603x; 3.2603x over previous
//
#include <hip/hip_runtime.h>
#include <hip/hip_bf16.h>

// Cos_RootHist_GLM — f32 in/out (verified passing round 10).
// This round: scan replaced by single-wave ring-FIR (no barriers):
//   256 ring slots in 4 VGPR/lane; coeff table in LDS; readlane broadcast;
//   log2-domain softplus; one-ahead OB prefetch (valid because hist[0]==0
//   exactly -> y_t never feeds y_{t+1}).

#define DEVINL __device__ __forceinline__

static constexpr int T_DATA = 20000;
static constexpr int N_E = 2000;
static constexpr int N_I = 500;
static constexpr int SUB = 15;
static constexpr int T_NO = 200;
static constexpr int NB = 19;

// ws layout (f32 offsets) — total 30592 f32 = 122,368 B
static constexpr int EKT_OFF = 0;      // [200][16]
static constexpr int IKT_OFF = 3200;   // [200][16]
static constexpr int HT_OFF  = 6400;   // 256
static constexpr int PRM_OFF = 6656;   // 0..14 wsub2, 16..30 theta, 33 scale, 34 vo
static constexpr int WE_OFF  = 6720;   // 2000
static constexpr int WI_OFF  = 8720;   // 500
static constexpr int IDXE_B  = 36880;  // byte off, 2000 uchar
static constexpr int IDXI_B  = 38880;  // byte off, 500 uchar
static constexpr int BT_OFF  = 9856;   // 20000 + pad (zeroed to 20736)
static constexpr int WS_END  = 30592;

DEVINL float fast_exp2(float x) {
#if __has_builtin(__builtin_amdgcn_exp2f)
  return __builtin_amdgcn_exp2f(x);
#else
  return exp2f(x);
#endif
}
DEVINL float fast_log2(float x) {
#if __has_builtin(__builtin_amdgcn_logf)
  return __builtin_amdgcn_logf(x);
#else
  return log2f(x);
#endif
}

DEVINL float softplus_f(float x) {
  float z = x * 1.44269504088896f;
  float l = 0.6931471805599453f * fast_log2(1.0f + fast_exp2(z));
  return (x > 16.0f) ? x : l;
}

// ---------------- prep ----------------
__global__ __launch_bounds__(256) void prep_kernel(
    const float* __restrict__ Cse, const float* __restrict__ Csi,
    const float* __restrict__ cosb, const float* __restrict__ Wsyn,
    const float* __restrict__ Wsub, const float* __restrict__ Vo,
    const float* __restrict__ Theta, const float* __restrict__ Whist,
    float* __restrict__ ws, float* __restrict__ outF) {
  const int tid = threadIdx.x;
  float* ekT = ws + EKT_OFF;
  float* ikT = ws + IKT_OFF;
  float* ht  = ws + HT_OFF;
  float* prm = ws + PRM_OFF;
  float* we  = ws + WE_OFF;
  float* wi  = ws + WI_OFF;
  unsigned char* idxe = (unsigned char*)ws + IDXE_B;
  unsigned char* idxi = (unsigned char*)ws + IDXI_B;
  float* bT  = ws + BT_OFF;

  for (int p = tid; p < SUB * T_NO; p += 256) {
    int s = p / T_NO, j = p - s * T_NO;
    float ae = 0.f, ai = 0.f;
    for (int b = 0; b < NB; ++b) {
      float cb = cosb[b * T_NO + j];
      ae = fmaf(Wsyn[(s * NB + b) * 2 + 0], cb, ae);
      ai = fmaf(Wsyn[(s * NB + b) * 2 + 1], cb, ai);
    }
    ekT[j * 16 + s] = ae;
    ikT[j * 16 + s] = ai;
    outF[p] = ae;
    outF[SUB * T_NO + p] = ai;
  }
  for (int j = tid; j < T_NO; j += 256) { ekT[j * 16 + 15] = 0.f; ikT[j * 16 + 15] = 0.f; }
  if (tid < 256) {
    float hv = 0.f;
    if (tid < T_NO) {
      for (int b = 0; b < NB; ++b) hv = fmaf(Whist[b], cosb[b * T_NO + tid], hv);
      outF[30 * T_NO + tid] = hv;
    }
    ht[tid] = (tid < T_NO) ? hv : 0.f;   // ht[0] == hist[0] == 0 exactly (masked basis col)
  }
  for (int n = tid; n < N_E; n += 256) {
    int id = 0; float w = 0.f;
    for (int s = 0; s < SUB; ++s) { float c = Cse[s * N_E + n]; if (c != 0.f) { id = s; w = c; } }
    idxe[n] = (unsigned char)id; we[n] = w;
  }
  for (int n = tid; n < N_I; n += 256) {
    int id = 0; float w = 0.f;
    for (int s = 0; s < SUB; ++s) { float c = Csi[s * N_I + n]; if (c != 0.f) { id = s; w = c; } }
    idxi[n] = (unsigned char)id; wi[n] = w;
  }
  if (tid < SUB) {
    float w = Wsub[tid];
    prm[tid] = w * w;
    prm[16 + tid] = Theta[tid];
  }
  if (tid == 0) {
    float w0 = Wsub[0];
    prm[33] = w0 * w0;
    prm[34] = Vo[0];
  }
  for (int p = T_DATA + tid; p < T_DATA + 736; p += 256) bT[p] = 0.f;
}

// ---------------- fused pool + conv + tree (block per 64 t's) ----------------
__global__ __launch_bounds__(256) void fused_kernel(
    const float* __restrict__ Se, const float* __restrict__ Si,
    float* __restrict__ ws, float* __restrict__ outNs) {
  __shared__ float cntE[264][16], cntI[264][16], synR[64][16];
  const int tid = threadIdx.x;
  const int t0 = blockIdx.x * 64;
  const unsigned char* idxe = (const unsigned char*)ws + IDXE_B;
  const unsigned char* idxi = (const unsigned char*)ws + IDXI_B;
  const float* we = ws + WE_OFF;
  const float* wi = ws + WI_OFF;

  for (int p = tid; p < 264 * 16; p += 256) {
    ((float*)cntE)[p] = 0.f;
    ((float*)cntI)[p] = 0.f;
  }
  __syncthreads();
  for (int r = 0; r < 263; ++r) {
    int g = t0 - 199 + r;
    if (g < 0 || g >= T_DATA) continue;
    const float* rowE = Se + (size_t)g * N_E;
    for (int n = tid; n < N_E; n += 256) {
      float v = rowE[n];
      if (v != 0.f) atomicAdd(&cntE[r][idxe[n]], v * we[n]);
    }
    const float* rowI = Si + (size_t)g * N_I;
    for (int n = tid; n < N_I; n += 256) {
      float v = rowI[n];
      if (v != 0.f) atomicAdd(&cntI[r][idxi[n]], v * wi[n]);
    }
  }
  __syncthreads();
  {
    const int q = tid >> 6, i = tid & 63;
    const float4* ekT = (const float4*)(ws + EKT_OFF);
    const float4* ikT = (const float4*)(ws + IKT_OFF);
    float4 acc = make_float4(0.f, 0.f, 0.f, 0.f);
    for (int d = 0; d < T_NO; ++d) {
      int r = i + 199 - d;
      float4 e = ekT[d * 4 + q], ce = ((const float4*)&cntE[r][0])[q];
      float4 ii = ikT[d * 4 + q], ci = ((const float4*)&cntI[r][0])[q];
      acc.x = fmaf(e.x, ce.x, fmaf(ii.x, ci.x, acc.x));
      acc.y = fmaf(e.y, ce.y, fmaf(ii.y, ci.y, acc.y));
      acc.z = fmaf(e.z, ce.z, fmaf(ii.z, ci.z, acc.z));
      acc.w = fmaf(e.w, ce.w, fmaf(ii.w, ci.w, acc.w));
    }
    ((float4*)&synR[i][0])[q] = acc;
  }
  __syncthreads();
  if (tid < 64) {
    int t = t0 + tid;
    if (t < T_DATA) {
      const float* prm = ws + PRM_OFF;
      float sv[16];
#pragma unroll
      for (int s = 0; s < 16; ++s) sv[s] = synR[tid][s];
      float ns[SUB];
#pragma unroll
      for (int j = SUB - 1; j >= 1; --j) {
        float x = sv[j] + prm[16 + j];
        if (2 * j + 1 < SUB) x = fmaf(prm[2 * j + 1], ns[2 * j + 1], x);
        if (2 * j + 2 < SUB) x = fmaf(prm[2 * j + 2], ns[2 * j + 2], x);
        ns[j] = softplus_f(x);
      }
      float b = sv[0] + prm[16];
      b = fmaf(prm[1], ns[1], b);
      b = fmaf(prm[2], ns[2], b);
      ws[BT_OFF + t] = b;
      outNs[(size_t)t * SUB] = 0.f;
#pragma unroll
      for (int s = 1; s < SUB; ++s) outNs[(size_t)t * SUB + s] = ns[s];
    }
  }
}

// ---------------- serial scan: single-wave ring-FIR, log2 domain ----------------
// Slot firing at time T lives in register a_{(K)} of lane (T mod 64) with
// rotation so a0 always fires. Coefficient stream rt[r*320+u] = ht[(64r-1-u)&255].
// OB prefetch one-ahead is exact because ht[0] == 0.
__global__ __launch_bounds__(64) void scan_kernel(const float* __restrict__ ws,
                                                  float* __restrict__ outV) {
  __shared__ float rt[4 * 320];
  const int lane = threadIdx.x;
  const float* ht = ws + HT_OFF;
  const float* prm = ws + PRM_OFF;
  const float* bT = ws + BT_OFF;
  for (int p = lane; p < 4 * 320; p += 64) {
    int r = p / 320, u = p - r * 320;
    rt[p] = ht[(64 * r - 1 - u) & 255];
  }
  __syncthreads();
  const float L2E = 1.44269504088896f;
  const float scale2 = 0.6931471805599453f * prm[33];  // ln2 * wsub2[0]
  const float vo = prm[34];
  float a0 = L2E * bT[lane];
  float a1 = L2E * bT[64 + lane];
  float a2 = L2E * bT[128 + lane];
  float a3 = L2E * bT[192 + lane];
  float cap = 0.f;
  int ub = (0 - lane) & 255;
  int t0 = 0;
  float OB = __shfl(a0, 0, 64);
  for (int chunk = 0; chunk < 313; ++chunk) {
    const int ph = chunk & 3;
    const int base0 = ((ph + 0) & 3) * 320 + ub;
    const int base1 = ((ph + 1) & 3) * 320 + ub;
    const int base2 = ((ph + 2) & 3) * 320 + ub;
    const int base3 = ((ph + 3) & 3) * 320 + ub;
    const float bnext = L2E * bT[t0 + 256 + lane];
#pragma unroll
    for (int i = 0; i < 64; ++i) {
      float ex = fast_exp2(OB);
      float lg = fast_log2(1.0f + ex);
      float y = (OB > 23.0f) ? OB : lg;       // y~_t = log2(1 + 2^z)
      bool own = (lane == i);
      a0 = own ? bnext : a0;                  // re-seed fired slot for t+256
      cap = own ? y : cap;                    // capture y~_{t0+lane}
      float OBn = (i < 63) ? __shfl(a0, i + 1, 64) : 0.f;  // pre-fma read: misses only ht[0]*y=0
      a0 = fmaf(rt[base0 + i], y, a0);
      a1 = fmaf(rt[base1 + i], y, a1);
      a2 = fmaf(rt[base2 + i], y, a2);
      a3 = fmaf(rt[base3 + i], y, a3);
      OB = OBn;
    }
    int t = t0 + lane;
    if (t < T_DATA) outV[t] = fmaf(cap, scale2, vo);   // ln2*w0^2*y~ + V_o
    float tmp = a0; a0 = a1; a1 = a2; a2 = a3; a3 = tmp;  // rotate roles
    ub = (ub + 64) & 255;
    t0 += 64;
    OB = __shfl(a0, 0, 64);                   // seed broadcast for next chunk
  }
}

// ---------------- sentinel ----------------
__global__ __launch_bounds__(256) void sentinel_kernel(float* __restrict__ outV, int code) {
  const int tid = threadIdx.x;
  for (int t = tid; t < T_DATA; t += 256) outV[t] = (float)code;
}

extern "C" void kernel_launch(void* const* d_in, const int* in_sizes, int n_in,
                              void* d_out, int out_size, void* d_ws, size_t ws_size,
                              hipStream_t stream) {
  const float* Se    = (const float*)d_in[0];
  const float* Si    = (const float*)d_in[1];
  const float* Cse   = (const float*)d_in[3];
  const float* Csi   = (const float*)d_in[4];
  const float* cosb  = (const float*)d_in[5];
  const float* Wsyn  = (const float*)d_in[6];
  const float* Wsub  = (const float*)d_in[7];
  const float* Vo    = (const float*)d_in[8];
  const float* Theta = (const float*)d_in[9];
  const float* Whist = (const float*)d_in[10];
  float* ws = (float*)d_ws;
  float* out = (float*)d_out;
  float* outV  = out;                          // final_V: 20000 f32
  float* outNs = out + T_DATA;                 // ns_out: 300000 f32
  float* outF  = out + T_DATA + T_DATA * SUB;  // out_filters: 6200 f32

  int force = 0;
  if (ws_size < (size_t)(WS_END * 4 + 2048)) force = 3000;
  else if (out_size != 326200) force = 3500;
  if (force) {
    sentinel_kernel<<<1, 256, 0, stream>>>(outV, force);
    return;
  }

  prep_kernel<<<1, 256, 0, stream>>>(Cse, Csi, cosb, Wsyn, Wsub, Vo, Theta, Whist, ws, outF);
  fused_kernel<<<313, 256, 0, stream>>>(Se, Si, ws, outNs);
  scan_kernel<<<1, 64, 0, stream>>>(ws, outV);
}

// Round 12
// 873.816 us; speedup vs baseline: 8.9442x; 2.7433x over previous
//
#include <hip/hip_runtime.h>
#include <hip/hip_bf16.h>

// Cos_RootHist_GLM — f32 in/out (passing since round 10).
// R12: split fused -> pool (5000 blk, wave/row, LDS atomics) + conv_tree
// (transposed LDS tiles, conflict-free); scan broadcast via readlane builtin
// (kills ds_bpermute latency), overflow guard dropped (z <= ~15.3 provable).

#define DEVINL __device__ __forceinline__

static constexpr int T_DATA = 20000;
static constexpr int N_E = 2000;
static constexpr int N_I = 500;
static constexpr int SUB = 15;
static constexpr int T_NO = 200;
static constexpr int NB = 19;

// ws layout (f32 offsets) — total 670720 f32 = 2.683 MB
static constexpr int EKT_OFF = 0;       // [200][16] e-kern transposed
static constexpr int IKT_OFF = 3200;    // [200][16]
static constexpr int HT_OFF  = 6400;    // 256
static constexpr int PRM_OFF = 6656;    // 0..14 wsub2, 16..30 theta, 33 scale, 34 vo
static constexpr int WE_OFF  = 6720;    // 2000
static constexpr int WI_OFF  = 8720;    // 500
static constexpr int IDXE_B  = 36880;   // byte off, 2000 uchar
static constexpr int IDXI_B  = 38880;   // byte off, 500 uchar
static constexpr int BT_OFF  = 9856;    // 20736 (zero-padded past 20000)
static constexpr int SYNE_OFF = 30720;  // [20000][16]
static constexpr int SYNI_OFF = 350720; // [20000][16]
static constexpr int WS_END  = 670720;

DEVINL float fast_exp2(float x) {
#if __has_builtin(__builtin_amdgcn_exp2f)
  return __builtin_amdgcn_exp2f(x);
#else
  return exp2f(x);
#endif
}
DEVINL float fast_log2(float x) {
#if __has_builtin(__builtin_amdgcn_logf)
  return __builtin_amdgcn_logf(x);
#else
  return log2f(x);
#endif
}
DEVINL float rlane(float v, int l) {
  return __builtin_bit_cast(float, __builtin_amdgcn_readlane(__builtin_bit_cast(int, v), l));
}

DEVINL float softplus_f(float x) {
  float z = x * 1.44269504088896f;
  float l = 0.6931471805599453f * fast_log2(1.0f + fast_exp2(z));
  return (x > 16.0f) ? x : l;
}

// ---------------- prep ----------------
__global__ __launch_bounds__(256) void prep_kernel(
    const float* __restrict__ Cse, const float* __restrict__ Csi,
    const float* __restrict__ cosb, const float* __restrict__ Wsyn,
    const float* __restrict__ Wsub, const float* __restrict__ Vo,
    const float* __restrict__ Theta, const float* __restrict__ Whist,
    float* __restrict__ ws, float* __restrict__ outF) {
  const int tid = threadIdx.x;
  float* ekT = ws + EKT_OFF;
  float* ikT = ws + IKT_OFF;
  float* ht  = ws + HT_OFF;
  float* prm = ws + PRM_OFF;
  float* we  = ws + WE_OFF;
  float* wi  = ws + WI_OFF;
  unsigned char* idxe = (unsigned char*)ws + IDXE_B;
  unsigned char* idxi = (unsigned char*)ws + IDXI_B;
  float* bT  = ws + BT_OFF;

  for (int p = tid; p < SUB * T_NO; p += 256) {
    int s = p / T_NO, j = p - s * T_NO;
    float ae = 0.f, ai = 0.f;
    for (int b = 0; b < NB; ++b) {
      float cb = cosb[b * T_NO + j];
      ae = fmaf(Wsyn[(s * NB + b) * 2 + 0], cb, ae);
      ai = fmaf(Wsyn[(s * NB + b) * 2 + 1], cb, ai);
    }
    ekT[j * 16 + s] = ae;
    ikT[j * 16 + s] = ai;
    outF[p] = ae;
    outF[SUB * T_NO + p] = ai;
  }
  for (int j = tid; j < T_NO; j += 256) { ekT[j * 16 + 15] = 0.f; ikT[j * 16 + 15] = 0.f; }
  if (tid < 256) {
    float hv = 0.f;
    if (tid < T_NO) {
      for (int b = 0; b < NB; ++b) hv = fmaf(Whist[b], cosb[b * T_NO + tid], hv);
      outF[30 * T_NO + tid] = hv;
    }
    ht[tid] = (tid < T_NO) ? hv : 0.f;   // ht[0] == hist[0] == 0 exactly
  }
  for (int n = tid; n < N_E; n += 256) {
    int id = 0; float w = 0.f;
    for (int s = 0; s < SUB; ++s) { float c = Cse[s * N_E + n]; if (c != 0.f) { id = s; w = c; } }
    idxe[n] = (unsigned char)id; we[n] = w;
  }
  for (int n = tid; n < N_I; n += 256) {
    int id = 0; float w = 0.f;
    for (int s = 0; s < SUB; ++s) { float c = Csi[s * N_I + n]; if (c != 0.f) { id = s; w = c; } }
    idxi[n] = (unsigned char)id; wi[n] = w;
  }
  if (tid < SUB) {
    float w = Wsub[tid];
    prm[tid] = w * w;
    prm[16 + tid] = Theta[tid];
  }
  if (tid == 0) {
    float w0 = Wsub[0];
    prm[33] = w0 * w0;
    prm[34] = Vo[0];
  }
  for (int p = T_DATA + tid; p < T_DATA + 736; p += 256) bT[p] = 0.f;
}

// ---------------- pool: wave per t-row, float4 loads, LDS atomics ----------------
__global__ __launch_bounds__(256) void pool_kernel(
    const float* __restrict__ Se, const float* __restrict__ Si,
    float* __restrict__ ws) {
  __shared__ float cnt[4][32];   // [wave][0:16 E | 16:32 I]
  const int lane = threadIdx.x & 63;
  const int w = threadIdx.x >> 6;
  const int t = blockIdx.x * 4 + w;
  if (lane < 32) cnt[w][lane] = 0.f;
  __syncthreads();
  const float* we = ws + WE_OFF;
  const float* wi = ws + WI_OFF;
  const unsigned int* ie = (const unsigned int*)((const char*)ws + IDXE_B);
  const unsigned int* ii = (const unsigned int*)((const char*)ws + IDXI_B);

  const float4* rowE = (const float4*)(Se + (size_t)t * N_E);   // 500 float4
#pragma unroll
  for (int k = 0; k < 8; ++k) {
    int c = k * 64 + lane;
    if (c < 500) {
      float4 v = rowE[c];
      unsigned int b = ie[c];
      if (v.x != 0.f) atomicAdd(&cnt[w][(b      ) & 0xFFu], v.x * we[c * 4 + 0]);
      if (v.y != 0.f) atomicAdd(&cnt[w][(b >>  8) & 0xFFu], v.y * we[c * 4 + 1]);
      if (v.z != 0.f) atomicAdd(&cnt[w][(b >> 16) & 0xFFu], v.z * we[c * 4 + 2]);
      if (v.w != 0.f) atomicAdd(&cnt[w][(b >> 24) & 0xFFu], v.w * we[c * 4 + 3]);
    }
  }
  const float4* rowI = (const float4*)(Si + (size_t)t * N_I);   // 125 float4
#pragma unroll
  for (int k = 0; k < 2; ++k) {
    int c = k * 64 + lane;
    if (c < 125) {
      float4 v = rowI[c];
      unsigned int b = ii[c];
      if (v.x != 0.f) atomicAdd(&cnt[w][16 + ((b      ) & 0xFFu)], v.x * wi[c * 4 + 0]);
      if (v.y != 0.f) atomicAdd(&cnt[w][16 + ((b >>  8) & 0xFFu)], v.y * wi[c * 4 + 1]);
      if (v.z != 0.f) atomicAdd(&cnt[w][16 + ((b >> 16) & 0xFFu)], v.z * wi[c * 4 + 2]);
      if (v.w != 0.f) atomicAdd(&cnt[w][16 + ((b >> 24) & 0xFFu)], v.w * wi[c * 4 + 3]);
    }
  }
  __syncthreads();
  if (lane < 16) {
    ws[SYNE_OFF + (size_t)t * 16 + lane] = cnt[w][lane];
    ws[SYNI_OFF + (size_t)t * 16 + lane] = cnt[w][16 + lane];
  }
}

// ---------------- conv + tree: transposed LDS tiles, conflict-free ----------------
__global__ __launch_bounds__(256) void conv_tree_kernel(float* __restrict__ ws,
                                                        float* __restrict__ outNs) {
  __shared__ float sE[16][272], sI[16][272];   // transposed, padded rows
  __shared__ float ekL[200 * 16], ikL[200 * 16];
  __shared__ float synR[64][16];
  const int tid = threadIdx.x;
  const int t0 = blockIdx.x * 64;

  for (int p = tid; p < 200 * 16; p += 256) { ekL[p] = ws[EKT_OFF + p]; ikL[p] = ws[IKT_OFF + p]; }
  for (int p = tid; p < 264 * 16; p += 256) {
    int o = p >> 4, s = p & 15;
    int g = t0 - 200 + o;
    bool ok = (g >= 0) && (g < T_DATA);
    sE[s][o] = ok ? ws[SYNE_OFF + (size_t)g * 16 + s] : 0.f;
    sI[s][o] = ok ? ws[SYNI_OFF + (size_t)g * 16 + s] : 0.f;
  }
  __syncthreads();
  {
    const int q = tid >> 6, i = tid & 63;
    const int s0 = q * 4;
    float ax = 0.f, ay = 0.f, az = 0.f, aw = 0.f;
    for (int j = 0; j < T_NO; ++j) {
      int o = i + 200 - j;
      float4 e = *(const float4*)&ekL[j * 16 + s0];   // uniform per quad-wave: broadcast
      float4 k = *(const float4*)&ikL[j * 16 + s0];
      ax = fmaf(e.x, sE[s0 + 0][o], fmaf(k.x, sI[s0 + 0][o], ax));
      ay = fmaf(e.y, sE[s0 + 1][o], fmaf(k.y, sI[s0 + 1][o], ay));
      az = fmaf(e.z, sE[s0 + 2][o], fmaf(k.z, sI[s0 + 2][o], az));
      aw = fmaf(e.w, sE[s0 + 3][o], fmaf(k.w, sI[s0 + 3][o], aw));
    }
    synR[i][s0 + 0] = ax;
    synR[i][s0 + 1] = ay;
    synR[i][s0 + 2] = az;
    synR[i][s0 + 3] = aw;
  }
  __syncthreads();
  if (tid < 64) {
    int t = t0 + tid;
    if (t < T_DATA) {
      const float* prm = ws + PRM_OFF;
      float sv[16];
#pragma unroll
      for (int s = 0; s < 16; ++s) sv[s] = synR[tid][s];
      float ns[SUB];
#pragma unroll
      for (int j = SUB - 1; j >= 1; --j) {
        float x = sv[j] + prm[16 + j];
        if (2 * j + 1 < SUB) x = fmaf(prm[2 * j + 1], ns[2 * j + 1], x);
        if (2 * j + 2 < SUB) x = fmaf(prm[2 * j + 2], ns[2 * j + 2], x);
        ns[j] = softplus_f(x);
      }
      float b = sv[0] + prm[16];
      b = fmaf(prm[1], ns[1], b);
      b = fmaf(prm[2], ns[2], b);
      ws[BT_OFF + t] = b;
      outNs[(size_t)t * SUB] = 0.f;
#pragma unroll
      for (int s = 1; s < SUB; ++s) outNs[(size_t)t * SUB + s] = ns[s];
    }
  }
}

// ---------------- serial scan: single-wave ring-FIR, log2 domain ----------------
// readlane broadcast (constant lane under unroll -> no LDS bpermute).
// No overflow guard: hist<=0, max|b|~10.5 -> z <= ~15.3 << 128.
__global__ __launch_bounds__(64) void scan_kernel(const float* __restrict__ ws,
                                                  float* __restrict__ outV) {
  __shared__ float rt[4 * 320];
  const int lane = threadIdx.x;
  const float* ht = ws + HT_OFF;
  const float* prm = ws + PRM_OFF;
  const float* bT = ws + BT_OFF;
  for (int p = lane; p < 4 * 320; p += 64) {
    int r = p / 320, u = p - r * 320;
    rt[p] = ht[(64 * r - 1 - u) & 255];
  }
  __syncthreads();
  const float L2E = 1.44269504088896f;
  const float scale2 = 0.6931471805599453f * prm[33];  // ln2 * wsub2[0]
  const float vo = prm[34];
  float a0 = L2E * bT[lane];
  float a1 = L2E * bT[64 + lane];
  float a2 = L2E * bT[128 + lane];
  float a3 = L2E * bT[192 + lane];
  float cap = 0.f;
  int ub = (0 - lane) & 255;
  int t0 = 0;
  float OB = rlane(a0, 0);
  for (int chunk = 0; chunk < 313; ++chunk) {
    const int ph = chunk & 3;
    const int base0 = ((ph + 0) & 3) * 320 + ub;
    const int base1 = ((ph + 1) & 3) * 320 + ub;
    const int base2 = ((ph + 2) & 3) * 320 + ub;
    const int base3 = ((ph + 3) & 3) * 320 + ub;
    const float bnext = L2E * bT[t0 + 256 + lane];
#pragma unroll
    for (int i = 0; i < 64; ++i) {
      float ex = fast_exp2(OB);
      float y = fast_log2(1.0f + ex);          // y~_t = log2(1 + 2^z)
      bool own = (lane == i);
      a0 = own ? bnext : a0;                   // re-seed fired slot for t+256
      cap = own ? y : cap;                     // capture y~_{t0+lane}
      float OBn = (i < 63) ? rlane(a0, i + 1) : 0.f;  // pre-fma: misses only ht[0]*y = 0
      a0 = fmaf(rt[base0 + i], y, a0);
      a1 = fmaf(rt[base1 + i], y, a1);
      a2 = fmaf(rt[base2 + i], y, a2);
      a3 = fmaf(rt[base3 + i], y, a3);
      OB = OBn;
    }
    int t = t0 + lane;
    if (t < T_DATA) outV[t] = fmaf(cap, scale2, vo);     // ln2*w0^2*y~ + V_o
    float tmp = a0; a0 = a1; a1 = a2; a2 = a3; a3 = tmp; // rotate roles
    ub = (ub + 64) & 255;
    t0 += 64;
    OB = rlane(a0, 0);
  }
}

// ---------------- sentinel ----------------
__global__ __launch_bounds__(256) void sentinel_kernel(float* __restrict__ outV, int code) {
  const int tid = threadIdx.x;
  for (int t = tid; t < T_DATA; t += 256) outV[t] = (float)code;
}

extern "C" void kernel_launch(void* const* d_in, const int* in_sizes, int n_in,
                              void* d_out, int out_size, void* d_ws, size_t ws_size,
                              hipStream_t stream) {
  const float* Se    = (const float*)d_in[0];
  const float* Si    = (const float*)d_in[1];
  const float* Cse   = (const float*)d_in[3];
  const float* Csi   = (const float*)d_in[4];
  const float* cosb  = (const float*)d_in[5];
  const float* Wsyn  = (const float*)d_in[6];
  const float* Wsub  = (const float*)d_in[7];
  const float* Vo    = (const float*)d_in[8];
  const float* Theta = (const float*)d_in[9];
  const float* Whist = (const float*)d_in[10];
  float* ws = (float*)d_ws;
  float* out = (float*)d_out;
  float* outV  = out;                          // final_V: 20000 f32
  float* outNs = out + T_DATA;                 // ns_out: 300000 f32
  float* outF  = out + T_DATA + T_DATA * SUB;  // out_filters: 6200 f32

  int force = 0;
  if (ws_size < (size_t)WS_END * 4 + 1024) force = 3000;
  else if (out_size != 326200) force = 3500;
  if (force) {
    sentinel_kernel<<<1, 256, 0, stream>>>(outV, force);
    return;
  }

  prep_kernel<<<1, 256, 0, stream>>>(Cse, Csi, cosb, Wsyn, Wsub, Vo, Theta, Whist, ws, outF);
  pool_kernel<<<5000, 256, 0, stream>>>(Se, Si, ws);
  conv_tree_kernel<<<313, 256, 0, stream>>>(ws, outNs);
  scan_kernel<<<1, 64, 0, stream>>>(ws, outV);
}